// Round 11
// baseline (361.342 us; speedup 1.0000x reference)
//
#include <hip/hip_runtime.h>
#include <math.h>

#define DIMX 2048
#define KV_RANK 512
#define Q_RANK 768
#define NH 16
#define D_NR 128
#define D_R 64
#define D_V 128
#define NB 8
#define NL 32
#define MAX_T 4096
#define STARTP (MAX_T - NL)      /* 4064 */
#define QK_DIM (D_NR + D_R)      /* 192 */
#define ATT_SCALE 0.07216878364870323f  /* 1/sqrt(192) */
#define RMS_EPS 1.1920929e-07f

typedef unsigned short u16;
typedef __attribute__((ext_vector_type(4))) unsigned short u16x4;
typedef __attribute__((ext_vector_type(8))) unsigned short u16x8;
typedef __attribute__((ext_vector_type(8))) short short8;
typedef __attribute__((ext_vector_type(4))) float f32x4;

#define GLOBAL_AS __attribute__((address_space(1)))
#define LDS_AS __attribute__((address_space(3)))

#define NDOWN 1344                 /* 768 + 576 fused down-proj N */
#define DPART ((long long)256 * NDOWN)   /* per-split partial stride */

__device__ inline u16 f2b(float f) {
    union { float f; unsigned u; } v; v.f = f;
    unsigned r = (v.u + 0x7fffu + ((v.u >> 16) & 1u)) >> 16;
    return (u16)r;
}
__device__ inline float b2f(u16 u) {
    union { unsigned u; float f; } v; v.u = ((unsigned)u) << 16; return v.f;
}

// ---------------------------------------------------------------------------
// bf16 MFMA GEMM, C = A * B^T (A (M,K), B (N,K), row-major bf16), fp32 acc.
// 2-phase double-buffered LDS K-loop, XOR k-chunk swizzle (both sides).
// OUTB: bf16 C (else fp32). GSWZ: XCD-chunked swizzle (nwg % 8 == 0).
// Two-level batch: z1 = z/nb2, z2 = z%nb2. Split-K via z2 K-offset strides.
// ---------------------------------------------------------------------------
template<int BM, int BN, bool OUTB, bool GSWZ>
__global__ __launch_bounds__(256) void gemm_mfma(
    const u16* __restrict__ A, const u16* __restrict__ B, void* __restrict__ Cv,
    int K, int lda, int ldb, int ldc,
    long long sA1, long long sA2, long long sB1, long long sB2,
    long long sC1, long long sC2, int nb2)
{
    constexpr int MFR = BM / 32;
    constexpr int NFR = BN / 32;
    int bx = blockIdx.x, by = blockIdx.y, bz = blockIdx.z;
    if (GSWZ) {
        int flat = bx + gridDim.x * (by + gridDim.y * bz);
        int nwg = gridDim.x * gridDim.y * gridDim.z;
        int lf = (flat & 7) * (nwg >> 3) + (flat >> 3);
        bx = lf % gridDim.x;
        int r = lf / gridDim.x;
        by = r % gridDim.y;
        bz = r / gridDim.y;
    }
    const int z1 = bz / nb2, z2 = bz % nb2;
    A += z1 * sA1 + z2 * sA2;
    B += z1 * sB1 + z2 * sB2;

    const int m0 = by * BM;
    const int n0 = bx * BN;
    const int tid = threadIdx.x;
    const int lane = tid & 63;
    const int wid = tid >> 6;
    const int wm = wid >> 1, wn = wid & 1;
    const int l15 = lane & 15;
    const int l4  = lane >> 4;

    __shared__ __align__(16) u16 As[2][BM * 32];
    __shared__ __align__(16) u16 Bs[2][BN * 32];

    constexpr int nA = BM / 16;
    constexpr int nB = BN / 16;

    auto stage = [&](int buf, int k0) {
        #pragma unroll
        for (int j = 0; j < nA / 4 + 1; ++j) {
            int jj = wid + j * 4;
            if (jj < nA) {
                int c = jj * 64 + lane;
                int row = c >> 2;
                int ksg = (c & 3) ^ ((row >> 1) & 3);
                const u16* src = A + (long long)(m0 + row) * lda + k0 + ksg * 8;
                __builtin_amdgcn_global_load_lds((const GLOBAL_AS void*)src,
                                                 (LDS_AS void*)&As[buf][jj * 512], 16, 0, 0);
            }
        }
        #pragma unroll
        for (int j = 0; j < nB / 4 + 1; ++j) {
            int jj = wid + j * 4;
            if (jj < nB) {
                int c = jj * 64 + lane;
                int row = c >> 2;
                int ksg = (c & 3) ^ ((row >> 1) & 3);
                const u16* src = B + (long long)(n0 + row) * ldb + k0 + ksg * 8;
                __builtin_amdgcn_global_load_lds((const GLOBAL_AS void*)src,
                                                 (LDS_AS void*)&Bs[buf][jj * 512], 16, 0, 0);
            }
        }
    };

    f32x4 acc[MFR][NFR];
    #pragma unroll
    for (int i = 0; i < MFR; ++i)
        #pragma unroll
        for (int j = 0; j < NFR; ++j)
            acc[i][j] = (f32x4)0.0f;

    const int nk = K >> 5;
    stage(0, 0);
    int cur = 0;
    for (int ki = 0; ki < nk; ++ki) {
        __syncthreads();
        if (ki + 1 < nk) stage(cur ^ 1, (ki + 1) << 5);

        short8 a[MFR], b[NFR];
        #pragma unroll
        for (int mf = 0; mf < MFR; ++mf) {
            int row = wm * 16 * MFR + mf * 16 + l15;
            int ksl = l4 ^ ((row >> 1) & 3);
            a[mf] = *(const short8*)&As[cur][row * 32 + ksl * 8];
        }
        #pragma unroll
        for (int nf = 0; nf < NFR; ++nf) {
            int row = wn * 16 * NFR + nf * 16 + l15;
            int ksl = l4 ^ ((row >> 1) & 3);
            b[nf] = *(const short8*)&Bs[cur][row * 32 + ksl * 8];
        }
        __builtin_amdgcn_s_setprio(1);
        #pragma unroll
        for (int mf = 0; mf < MFR; ++mf)
            #pragma unroll
            for (int nf = 0; nf < NFR; ++nf)
                acc[mf][nf] = __builtin_amdgcn_mfma_f32_16x16x32_bf16(
                    a[mf], b[nf], acc[mf][nf], 0, 0, 0);
        __builtin_amdgcn_s_setprio(0);
        cur ^= 1;
    }

    if (OUTB) {
        u16* C = (u16*)Cv + z1 * sC1 + z2 * sC2;
        #pragma unroll
        for (int mf = 0; mf < MFR; ++mf)
            #pragma unroll
            for (int nf = 0; nf < NFR; ++nf) {
                int r0 = m0 + wm * 16 * MFR + mf * 16 + l4 * 4;
                int c0 = n0 + wn * 16 * NFR + nf * 16 + l15;
                #pragma unroll
                for (int r = 0; r < 4; ++r)
                    C[(long long)(r0 + r) * ldc + c0] = f2b(acc[mf][nf][r]);
            }
    } else {
        float* C = (float*)Cv + z1 * sC1 + z2 * sC2;
        #pragma unroll
        for (int mf = 0; mf < MFR; ++mf)
            #pragma unroll
            for (int nf = 0; nf < NFR; ++nf) {
                int r0 = m0 + wm * 16 * MFR + mf * 16 + l4 * 4;
                int c0 = n0 + wn * 16 * NFR + nf * 16 + l15;
                #pragma unroll
                for (int r = 0; r < 4; ++r)
                    C[(long long)(r0 + r) * ldc + c0] = acc[mf][nf][r];
            }
    }
}

// ---------------------------------------------------------------------------
// Fused flash attention: per block = 32 Q-rows (one head) x t-split 1024.
// S-phase: 9 dbuf K-chunks (BK=64) from bcat; exp+mask -> Ps (LDS, octet
// XOR-swizzle); PV: B-frags direct from kvcT global; 32x512 fp32 acc.
// Writes unnormalized O partial [b][ts][512][512] and rowsum [ts][b][512].
// ---------------------------------------------------------------------------
__global__ __launch_bounds__(256) void attn_fused(
    const u16* __restrict__ qp,    // (b,512,576)
    const u16* __restrict__ bcat,  // (b,4096,576)
    const u16* __restrict__ kvcT,  // (b,512,4096)
    float* __restrict__ opart,     // [b][ts][512][512]
    float* __restrict__ rspart)    // [ts][b][512]
{
    int flat = blockIdx.x + gridDim.x * (blockIdx.y + gridDim.y * blockIdx.z);
    int lf = (flat & 7) * 64 + (flat >> 3);       // nwg = 512, XCD-chunked
    const int mb = lf & 15;
    const int ts = (lf >> 4) & 3;
    const int b  = lf >> 6;
    const int m0 = mb * 32;

    const int tid = threadIdx.x;
    const int lane = tid & 63;
    const int w = tid >> 6;
    const int l15 = lane & 15;
    const int l4  = lane >> 4;

    __shared__ __align__(16) u16 Qs[32 * 584];    // +8 pad: conflict-free a-frags
    __shared__ __align__(16) u16 Ks[2][128 * 64];
    __shared__ __align__(16) u16 Ps[32 * 128];
    __shared__ float rs_l[4][32];

    // load Q tile (32x576)
    const u16* qsrc = qp + ((long long)b * 512 + m0) * 576;
    #pragma unroll
    for (int i = 0; i < 9; ++i) {
        int idx = i * 256 + tid;                  // < 2304
        int row = idx / 72, c8 = idx % 72;
        *(u16x8*)&Qs[row * 584 + c8 * 8] = *(const u16x8*)&qsrc[(long long)row * 576 + c8 * 8];
    }

    const int tb0 = ts * 1024;
    const u16* Kbase = bcat + (long long)b * MAX_T * 576;
    const u16* Vbase = kvcT + (long long)b * 512 * 4096;

    auto stageK = [&](int buf, int tile, int k0) {
        #pragma unroll
        for (int j = 0; j < 4; ++j) {
            int c = (w * 4 + j) * 64 + lane;       // octet index 0..1023
            int row = c >> 3;
            int g = (c & 7) ^ (row & 7);           // pre-swizzled source octet
            const u16* src = Kbase + (long long)(tb0 + tile * 128 + row) * 576 + k0 + g * 8;
            __builtin_amdgcn_global_load_lds((const GLOBAL_AS void*)src,
                                             (LDS_AS void*)&Ks[buf][c * 8], 16, 0, 0);
        }
    };

    f32x4 acc[2][8];
    #pragma unroll
    for (int i = 0; i < 2; ++i)
        #pragma unroll
        for (int j = 0; j < 8; ++j)
            acc[i][j] = (f32x4)0.0f;
    float rsum[2][4];
    #pragma unroll
    for (int i = 0; i < 2; ++i)
        #pragma unroll
        for (int r = 0; r < 4; ++r)
            rsum[i][r] = 0.f;

    stageK(0, 0, 0);
    int cur = 0;
    for (int tile = 0; tile < 8; ++tile) {
        f32x4 sacc[2][2];
        #pragma unroll
        for (int i = 0; i < 2; ++i)
            #pragma unroll
            for (int j = 0; j < 2; ++j)
                sacc[i][j] = (f32x4)0.0f;

        for (int kc = 0; kc < 9; ++kc) {
            __syncthreads();                       // Ks[cur] staged; prior reads done
            if (kc < 8) stageK(cur ^ 1, tile, (kc + 1) * 64);
            else if (tile < 7) stageK(cur ^ 1, tile + 1, 0);

            __builtin_amdgcn_s_setprio(1);
            #pragma unroll
            for (int kk = 0; kk < 2; ++kk) {
                int kg = kc * 64 + kk * 32;
                short8 a0 = *(const short8*)&Qs[(l15) * 584 + kg + l4 * 8];
                short8 a1 = *(const short8*)&Qs[(16 + l15) * 584 + kg + l4 * 8];
                #pragma unroll
                for (int tf = 0; tf < 2; ++tf) {
                    int trow = w * 32 + tf * 16 + l15;
                    int slot = (kk * 4 + l4) ^ (trow & 7);
                    short8 bb = *(const short8*)&Ks[cur][trow * 64 + slot * 8];
                    sacc[0][tf] = __builtin_amdgcn_mfma_f32_16x16x32_bf16(a0, bb, sacc[0][tf], 0, 0, 0);
                    sacc[1][tf] = __builtin_amdgcn_mfma_f32_16x16x32_bf16(a1, bb, sacc[1][tf], 0, 0, 0);
                }
            }
            __builtin_amdgcn_s_setprio(0);
            cur ^= 1;
        }

        // exp + mask -> Ps (safe: all waves passed kc=0 barrier => prior PV reads done)
        #pragma unroll
        for (int mf = 0; mf < 2; ++mf)
            #pragma unroll
            for (int tf = 0; tf < 2; ++tf)
                #pragma unroll
                for (int r = 0; r < 4; ++r) {
                    int m = mf * 16 + l4 * 4 + r;          // 0..31
                    int tl = w * 32 + tf * 16 + l15;       // t within tile
                    int tg = tb0 + tile * 128 + tl;        // global t
                    float p = (tg <= STARTP + (m & 31)) ? __expf(sacc[mf][tf][r] * ATT_SCALE) : 0.f;
                    u16 pb2 = f2b(p);
                    rsum[mf][r] += b2f(pb2);
                    int slot = (tl >> 3) ^ (m & 15);
                    Ps[m * 128 + (slot << 3) + (tl & 7)] = pb2;
                }
        __syncthreads();                           // Ps visible

        // PV: acc += P (32 x 128t) * V^T, B-frags direct from kvcT
        #pragma unroll
        for (int tc = 0; tc < 4; ++tc) {
            short8 a[2];
            #pragma unroll
            for (int mf = 0; mf < 2; ++mf) {
                int m = mf * 16 + l15;
                int slot = (tc * 4 + l4) ^ (m & 15);
                a[mf] = *(const short8*)&Ps[m * 128 + (slot << 3)];
            }
            long long tg0 = tb0 + tile * 128 + tc * 32 + l4 * 8;
            #pragma unroll
            for (int nf = 0; nf < 8; ++nf) {
                int n = w * 128 + nf * 16 + l15;
                short8 bb = *(const short8*)&Vbase[(long long)n * 4096 + tg0];
                acc[0][nf] = __builtin_amdgcn_mfma_f32_16x16x32_bf16(a[0], bb, acc[0][nf], 0, 0, 0);
                acc[1][nf] = __builtin_amdgcn_mfma_f32_16x16x32_bf16(a[1], bb, acc[1][nf], 0, 0, 0);
            }
        }
    }

    // epilogue: O partial
    float* od = opart + ((long long)b * 4 + ts) * 262144 + (long long)m0 * 512;
    #pragma unroll
    for (int mf = 0; mf < 2; ++mf)
        #pragma unroll
        for (int nf = 0; nf < 8; ++nf)
            #pragma unroll
            for (int r = 0; r < 4; ++r)
                od[(long long)(mf * 16 + l4 * 4 + r) * 512 + w * 128 + nf * 16 + l15] = acc[mf][nf][r];

    // rowsum partial
    #pragma unroll
    for (int mf = 0; mf < 2; ++mf)
        #pragma unroll
        for (int r = 0; r < 4; ++r) {
            float v = rsum[mf][r];
            v += __shfl_xor(v, 1);
            v += __shfl_xor(v, 2);
            v += __shfl_xor(v, 4);
            v += __shfl_xor(v, 8);
            if (l15 == 0) rs_l[w][mf * 16 + l4 * 4 + r] = v;
        }
    __syncthreads();
    if (tid < 32)
        rspart[((long long)ts * 8 + b) * 512 + m0 + tid] =
            rs_l[0][tid] + rs_l[1][tid] + rs_l[2][tid] + rs_l[3][tid];
}

// ---------------------------------------------------------------------------
struct Segs {
    const float* src[6];
    u16* dst[6];
    int n4[6];
};
__global__ __launch_bounds__(256) void f2b_multi(Segs s)
{
    int seg = blockIdx.y;
    int i = blockIdx.x * 256 + threadIdx.x;
    if (i >= s.n4[seg]) return;
    float4 v = ((const float4*)s.src[seg])[i];
    u16x4 o = { f2b(v.x), f2b(v.y), f2b(v.z), f2b(v.w) };
    ((u16x4*)s.dst[seg])[i] = o;
}

// Sum 4 split-K partials (cols 0..767 of fused down output), RMS-norm -> bf16.
__global__ __launch_bounds__(256) void rms_reduce(const float* __restrict__ part,
                                                  const float* __restrict__ w,
                                                  u16* __restrict__ outb)
{
    const int row = blockIdx.x;          // 0..255
    const int tid = threadIdx.x;
    __shared__ float red[256];
    float val[3];
    float s = 0.f;
    #pragma unroll
    for (int j = 0; j < 3; ++j) {
        int i = tid + j * 256;
        long long off = (long long)row * NDOWN + i;
        float v = part[off] + part[DPART + off] + part[2 * DPART + off] + part[3 * DPART + off];
        val[j] = v;
        s += v * v;
    }
    red[tid] = s; __syncthreads();
    for (int off = 128; off > 0; off >>= 1) {
        if (tid < off) red[tid] += red[tid + off];
        __syncthreads();
    }
    float scale = rsqrtf(red[0] / (float)Q_RANK + RMS_EPS);
    u16* ob = outb + (long long)row * Q_RANK;
    #pragma unroll
    for (int j = 0; j < 3; ++j) {
        int i = tid + j * 256;
        ob[i] = f2b(val[j] * scale * w[i]);
    }
}

// Transpose w_kv_up[:, :128] per head: fp32 (h,128,512) -> bf16 wuT (h,512,128)
__global__ __launch_bounds__(256) void wuT_kernel(const float* __restrict__ w,
                                                  u16* __restrict__ outp)
{
    __shared__ u16 T[64][65];
    const int h = blockIdx.z;
    const int y0 = blockIdx.y * 64;
    const int x0 = blockIdx.x * 64;
    const int tid = threadIdx.x;
    #pragma unroll
    for (int i = 0; i < 16; ++i) {
        int lin = i * 256 + tid;
        int r = lin >> 6, c = lin & 63;
        T[c][r] = f2b(w[((long long)h * 256 + y0 + r) * 512 + x0 + c]);
    }
    __syncthreads();
    #pragma unroll
    for (int i = 0; i < 16; ++i) {
        int lin = i * 256 + tid;
        int r = lin >> 6, c = lin & 63;
        outp[((long long)h * 512 + x0 + r) * 128 + y0 + c] = T[r][c];
    }
}

// Sum 4 kv split-K partials; write new bcat rows (latent + roped k_rope).
__global__ __launch_bounds__(256) void bcat_new_reduce(const float* __restrict__ part,
                                                       const float* __restrict__ fc,
                                                       const float* __restrict__ fs,
                                                       u16* __restrict__ bcat)
{
    const int bl = blockIdx.x;        // 0..255
    const int b = bl >> 5, l = bl & 31;
    const int t = threadIdx.x;
    if (t >= 144) return;
    long long off = (long long)bl * NDOWN + 768 + 4 * t;
    float4 v0 = *(const float4*)(part + off);
    float4 v1 = *(const float4*)(part + DPART + off);
    float4 v2 = *(const float4*)(part + 2 * DPART + off);
    float4 v3 = *(const float4*)(part + 3 * DPART + off);
    float4 v = { v0.x + v1.x + v2.x + v3.x, v0.y + v1.y + v2.y + v3.y,
                 v0.z + v1.z + v2.z + v3.z, v0.w + v1.w + v2.w + v3.w };
    u16* dst = bcat + ((long long)b * MAX_T + STARTP + l) * 576;
    if (t < 128) {
        u16x4 o = { f2b(v.x), f2b(v.y), f2b(v.z), f2b(v.w) };
        ((u16x4*)dst)[t] = o;
    } else {
        int g = t - 128;
        float c0 = fc[l * 32 + 2 * g],     s0 = fs[l * 32 + 2 * g];
        float c1 = fc[l * 32 + 2 * g + 1], s1 = fs[l * 32 + 2 * g + 1];
        u16x4 o = { f2b(v.x * c0 - v.y * s0), f2b(v.x * s0 + v.y * c0),
                    f2b(v.z * c1 - v.w * s1), f2b(v.z * s1 + v.w * c1) };
        *(u16x4*)(dst + 512 + 4 * g) = o;
    }
}

// ---------------------------------------------------------------------------
// Cache prep, 16 B stores (round 8). XOR-swizzled LDS.
// ---------------------------------------------------------------------------
__global__ __launch_bounds__(256) void prep_cache(const float* __restrict__ kvc,
                                                  const float* __restrict__ krc,
                                                  u16* __restrict__ bcat,
                                                  u16* __restrict__ kvcT)
{
    const int b = blockIdx.z;
    const int t0 = blockIdx.y * 64;
    const int tid = threadIdx.x;

    if (blockIdx.x == 8) {
        #pragma unroll
        for (int i = 0; i < 2; ++i) {
            int lin = i * 256 + tid;
            int r = lin >> 3, c8 = lin & 7;
            int t = t0 + r;
            if (t >= STARTP) continue;
            const float* src = krc + ((long long)b * MAX_T + t) * D_R + 8 * c8;
            float4 v0 = *(const float4*)src;
            float4 v1 = *(const float4*)(src + 4);
            u16x8 o = { f2b(v0.x), f2b(v0.y), f2b(v0.z), f2b(v0.w),
                        f2b(v1.x), f2b(v1.y), f2b(v1.z), f2b(v1.w) };
            *(u16x8*)(bcat + ((long long)b * MAX_T + t) * 576 + 512 + 8 * c8) = o;
        }
        return;
    }

    __shared__ u16 T[64 * 64];
    const int k0 = blockIdx.x * 64;

    #pragma unroll
    for (int i = 0; i < 2; ++i) {
        int lin = i * 256 + tid;
        int r = lin >> 3, c8 = lin & 7;
        int t = t0 + r;
        u16x4 oa, ob;
        if (t < STARTP) {
            const float* src = kvc + ((long long)b * MAX_T + t) * KV_RANK + k0 + 8 * c8;
            float4 v0 = *(const float4*)src;
            float4 v1 = *(const float4*)(src + 4);
            oa[0] = f2b(v0.x); oa[1] = f2b(v0.y); oa[2] = f2b(v0.z); oa[3] = f2b(v0.w);
            ob[0] = f2b(v1.x); ob[1] = f2b(v1.y); ob[2] = f2b(v1.z); ob[3] = f2b(v1.w);
            u16x8 o = { oa[0], oa[1], oa[2], oa[3], ob[0], ob[1], ob[2], ob[3] };
            *(u16x8*)(bcat + ((long long)b * MAX_T + t) * 576 + k0 + 8 * c8) = o;
        } else {
            const u16* s = bcat + ((long long)b * MAX_T + t) * 576 + k0 + 8 * c8;
            oa = *(const u16x4*)s;
            ob = *(const u16x4*)(s + 4);
        }
        int tg = r >> 2, te = r & 3;
        int c4a = 2 * c8, c4b = 2 * c8 + 1;
        int cola = ((tg ^ c4a) << 2) + te;
        int colb = ((tg ^ c4b) << 2) + te;
        #pragma unroll
        for (int j = 0; j < 4; ++j) {
            T[(4 * c4a + j) * 64 + cola] = oa[j];
            T[(4 * c4b + j) * 64 + colb] = ob[j];
        }
    }
    __syncthreads();

    u16* outp = kvcT + ((long long)b * KV_RANK + k0) * MAX_T + t0;
    #pragma unroll
    for (int i = 0; i < 2; ++i) {
        int lin = i * 256 + tid;
        int k = lin >> 3, c8 = lin & 7;
        int s = k >> 2;
        u16x4 va = *(const u16x4*)&T[k * 64 + (((2 * c8) ^ s) << 2)];
        u16x4 vb = *(const u16x4*)&T[k * 64 + (((2 * c8 + 1) ^ s) << 2)];
        u16x8 o = { va[0], va[1], va[2], va[3], vb[0], vb[1], vb[2], vb[3] };
        *(u16x8*)(outp + (long long)k * MAX_T + 8 * c8) = o;
    }
}

// roped q_rope (bf16 q in) -> qprimeb[b,h,l,512:576]
__global__ __launch_bounds__(256) void rope_q(const u16* __restrict__ qb,
                                              const float* __restrict__ fc,
                                              const float* __restrict__ fs,
                                              u16* __restrict__ qprimeb)
{
    int idx = blockIdx.x * 256 + threadIdx.x;
    int i = idx & 31;
    int h = (idx >> 5) & (NH - 1);
    int l = (idx >> 9) & (NL - 1);
    int b = idx >> 14;
    const u16* src = qb + (long long)(b * NL + l) * 3072 + h * QK_DIM + D_NR + 2 * i;
    float xr = b2f(src[0]), xi = b2f(src[1]);
    float c = fc[l * 32 + i], s = fs[l * 32 + i];
    u16* dst = qprimeb + ((long long)(b * NH + h) * NL + l) * 576 + 512 + 2 * i;
    dst[0] = f2b(xr * c - xi * s);
    dst[1] = f2b(xr * s + xi * c);
}

// Sum 4 PV t-split partials, normalize by summed rowsum -> bf16 o_hb.
__global__ __launch_bounds__(256) void reduce_pv(const float* __restrict__ part,
                                                 const float* __restrict__ rsp,
                                                 u16* __restrict__ o_hb)
{
    int idx = blockIdx.x * 256 + threadIdx.x;     // < 524288
    int b = idx >> 16;
    int i4 = idx & 65535;
    int m = i4 >> 7;                               // row within b
    const float* p = part + (long long)b * 1048576 + 4 * i4;
    float4 v0 = *(const float4*)p;
    float4 v1 = *(const float4*)(p + 262144);
    float4 v2 = *(const float4*)(p + 524288);
    float4 v3 = *(const float4*)(p + 786432);
    float denom = rsp[b * 512 + m] + rsp[4096 + b * 512 + m]
                + rsp[8192 + b * 512 + m] + rsp[12288 + b * 512 + m];
    float inv = 1.0f / denom;
    u16x4 o = { f2b((v0.x + v1.x + v2.x + v3.x) * inv),
                f2b((v0.y + v1.y + v2.y + v3.y) * inv),
                f2b((v0.z + v1.z + v2.z + v3.z) * inv),
                f2b((v0.w + v1.w + v2.w + v3.w) * inv) };
    ((u16x4*)(o_hb + (long long)b * 262144))[i4] = o;
}

// Sum 4 out-proj split-K partials -> fp32 out. 131072 float4 groups.
__global__ __launch_bounds__(256) void reduce_out(const float* __restrict__ part,
                                                  float* __restrict__ out)
{
    int idx = blockIdx.x * 256 + threadIdx.x;     // < 131072
    const float* p = part + 4 * (long long)idx;
    float4 v0 = *(const float4*)p;
    float4 v1 = *(const float4*)(p + 524288);
    float4 v2 = *(const float4*)(p + 1048576);
    float4 v3 = *(const float4*)(p + 1572864);
    float4 o = { v0.x + v1.x + v2.x + v3.x, v0.y + v1.y + v2.y + v3.y,
                 v0.z + v1.z + v2.z + v3.z, v0.w + v1.w + v2.w + v3.w };
    ((float4*)out)[idx] = o;
}

extern "C" void kernel_launch(void* const* d_in, const int* in_sizes, int n_in,
                              void* d_out, int out_size, void* d_ws, size_t ws_size,
                              hipStream_t stream)
{
    const float* x        = (const float*)d_in[0];
    const float* fc       = (const float*)d_in[2];
    const float* fs       = (const float*)d_in[3];
    const float* kvc      = (const float*)d_in[5];
    const float* krc      = (const float*)d_in[6];
    const float* w_kv_down= (const float*)d_in[7];
    const float* w_q_down = (const float*)d_in[8];
    const float* rms_q_w  = (const float*)d_in[9];
    const float* w_q_up   = (const float*)d_in[10];
    const float* w_kv_up  = (const float*)d_in[11];
    const float* w_out    = (const float*)d_in[12];
    float* out            = (float*)d_out;

    // ---- workspace layout ----
    float* down_part = (float*)d_ws;             // 1376256 f (dead after step 5)
    float* rs_part   = down_part;                // 16384 f, alias (used later)
    float* pv_part   = down_part + 1376256;      // 8388608 f = [b][ts][512][512]
    u16* base      = (u16*)(pv_part + 8388608);
    u16* xb      = base;                 base += 524288;    // 256x2048
    u16* qdb     = base;                 base += 196608;    // 256x768
    u16* qb      = base;                 base += 786432;    // 256x3072
    u16* qprimeb = base;                 base += 2359296;   // (b,h,l,576)
    u16* wqkv_b  = base;                 base += 2752512;   // [w_q_down;w_kv_down]
    u16* wqu_b   = base;                 base += 2359296;   // 3072x768
    u16* wkvu_b  = base;                 base += 2097152;   // 4096x512
    u16* wout_b  = base;                 base += 4194304;   // 2048x2048
    u16* wuT     = base;                 base += 1048576;   // (h,512,128)
    u16* bcat    = base;                 base += 18874368;  // (b,4096,576)
    u16* kvcT    = base;                 base += 16777216;  // (b,512,4096)
    u16* o_hb    = base;                 base += 2097152;   // (b,512,512)
    u16* o_upb   = base;                 base += 524288;    // 256x2048
    float* out_part = (float*)kvcT;   // 8 MB, after attn (kvcT dead)

    // 1) fp32->bf16 conversions
    Segs segs;
    segs.src[0] = x;         segs.dst[0] = xb;                  segs.n4[0] = 131072;
    segs.src[1] = w_q_down;  segs.dst[1] = wqkv_b;              segs.n4[1] = 393216;
    segs.src[2] = w_q_up;    segs.dst[2] = wqu_b;               segs.n4[2] = 589824;
    segs.src[3] = w_kv_down; segs.dst[3] = wqkv_b + 768 * 2048; segs.n4[3] = 294912;
    segs.src[4] = w_kv_up;   segs.dst[4] = wkvu_b;              segs.n4[4] = 524288;
    segs.src[5] = w_out;     segs.dst[5] = wout_b;              segs.n4[5] = 1048576;
    f2b_multi<<<dim3(4096, 6), 256, 0, stream>>>(segs);

    wuT_kernel<<<dim3(8, 2, 16), 256, 0, stream>>>(w_kv_up, wuT);

    // 2) fused down-proj split-K=4
    gemm_mfma<32, 64, false, true><<<dim3(21, 8, 4), 256, 0, stream>>>(
        xb, wqkv_b, down_part, 512, 2048, 2048, NDOWN,
        0LL, 512LL, 0LL, 512LL, 0LL, DPART, 4);
    // 3) reduce + RMS -> bf16
    rms_reduce<<<256, 256, 0, stream>>>(down_part, rms_q_w, qdb);
    // 4) q = qn @ w_q_up^T  (256,3072,768) bf16
    gemm_mfma<32, 64, true, true><<<dim3(48, 8, 1), 256, 0, stream>>>(
        qdb, wqu_b, qb, 768, 768, 768, 3072, 0, 0, 0, 0, 0, 0, 1);
    // 5) reduce kv part + new bcat rows
    bcat_new_reduce<<<256, 256, 0, stream>>>(down_part, fc, fs, bcat);
    // 6) cache prep
    prep_cache<<<dim3(9, 64, 8), 256, 0, stream>>>(kvc, krc, bcat, kvcT);

    // 7) q_abs per (b,h); rope
    gemm_mfma<32, 128, true, true><<<dim3(4, 1, 128), 256, 0, stream>>>(
        qb, wuT, qprimeb, 128, 3072, 128, 576,
        98304LL, 192LL, 0LL, 65536LL, 294912LL, 18432LL, 16);
    rope_q<<<512, 256, 0, stream>>>(qb, fc, fs, qprimeb);

    // 8) fused attention: scores+exp+mask+PV+rowsum, t-split 4
    attn_fused<<<dim3(16, 4, 8), 256, 0, stream>>>(
        qprimeb, bcat, kvcT, pv_part, rs_part);
    // 9) reduce + normalize -> bf16 o_hb
    reduce_pv<<<2048, 256, 0, stream>>>(pv_part, rs_part, o_hb);

    // 10) o_up per (b,h)
    gemm_mfma<32, 64, true, true><<<dim3(2, 1, 128), 256, 0, stream>>>(
        o_hb, wkvu_b + 128 * 512, o_upb, 512, 512, 512, 2048,
        262144LL, 16384LL, 0LL, 131072LL, 65536LL, 128LL, 16);
    // 11) out-proj split-K=4, reduce -> out
    gemm_mfma<32, 64, false, true><<<dim3(32, 8, 4), 256, 0, stream>>>(
        o_upb, wout_b, out_part, 512, 2048, 2048, 2048,
        0LL, 512LL, 0LL, 512LL, 0LL, 524288LL, 4);
    reduce_out<<<512, 256, 0, stream>>>(out_part, out);
}

// Round 12
// 314.761 us; speedup vs baseline: 1.1480x; 1.1480x over previous
//
#include <hip/hip_runtime.h>
#include <math.h>

#define DIMX 2048
#define KV_RANK 512
#define Q_RANK 768
#define NH 16
#define D_NR 128
#define D_R 64
#define D_V 128
#define NB 8
#define NL 32
#define MAX_T 4096
#define STARTP (MAX_T - NL)      /* 4064 */
#define QK_DIM (D_NR + D_R)      /* 192 */
#define ATT_SCALE 0.07216878364870323f  /* 1/sqrt(192) */
#define RMS_EPS 1.1920929e-07f

typedef unsigned short u16;
typedef __attribute__((ext_vector_type(4))) unsigned short u16x4;
typedef __attribute__((ext_vector_type(8))) unsigned short u16x8;
typedef __attribute__((ext_vector_type(8))) short short8;
typedef __attribute__((ext_vector_type(4))) float f32x4;

#define GLOBAL_AS __attribute__((address_space(1)))
#define LDS_AS __attribute__((address_space(3)))

#define NDOWN 1344                 /* 768 + 576 fused down-proj N */
#define DPART ((long long)256 * NDOWN)   /* per-split partial stride */

__device__ inline u16 f2b(float f) {
    union { float f; unsigned u; } v; v.f = f;
    unsigned r = (v.u + 0x7fffu + ((v.u >> 16) & 1u)) >> 16;
    return (u16)r;
}
__device__ inline float b2f(u16 u) {
    union { unsigned u; float f; } v; v.u = ((unsigned)u) << 16; return v.f;
}

// ---------------------------------------------------------------------------
// bf16 MFMA GEMM, C = A * B^T (A (M,K), B (N,K), row-major bf16), fp32 acc.
// OUTMODE: 0 = fp32 C, 1 = bf16 C, 2 = attention epilogue (exp+mask+rowsum).
// DEEP=false: 2-phase dbuf, __syncthreads per K-step (vmcnt(0) drain).
// DEEP=true : 3-buffer rotation with COUNTED vmcnt across raw s_barrier (T4):
//   per iter: wait vmcnt(LPW) (buffer r's loads retired, next buffer's stay
//   in flight), s_barrier, sched_barrier(0), ds_read buf r, issue stage of
//   buf (ki+2)%3 (overwrites the buf read at ki-1 - all waves past barrier
//   => their reads retired before their MFMA), MFMA. Requires uniform
//   loads/wave (nA%4==0 && nB%4==0).
// LDS K-chunk XOR swizzle (both sides): slot ksl holds chunk ksl^((row>>1)&3).
// GSWZ: XCD-chunked swizzle (nwg % 8 == 0). Two-level batch z1=z/nb2,
// z2=z%nb2. Split-K via z2 K-offset strides.
// ---------------------------------------------------------------------------
template<int BM, int BN, int OUTMODE, bool GSWZ, bool DEEP>
__global__ __launch_bounds__(256) void gemm_mfma(
    const u16* __restrict__ A, const u16* __restrict__ B, void* __restrict__ Cv,
    float* __restrict__ rs,
    int K, int lda, int ldb, int ldc,
    long long sA1, long long sA2, long long sB1, long long sB2,
    long long sC1, long long sC2, int nb2)
{
    constexpr int MFR = BM / 32;
    constexpr int NFR = BN / 32;
    constexpr int nA = BM / 16;
    constexpr int nB = BN / 16;
    constexpr int NBUF = DEEP ? 3 : 2;
    static_assert(!DEEP || (nA % 4 == 0 && nB % 4 == 0), "DEEP needs uniform loads/wave");

    int bx = blockIdx.x, by = blockIdx.y, bz = blockIdx.z;
    if (GSWZ) {
        int flat = bx + gridDim.x * (by + gridDim.y * bz);
        int nwg = gridDim.x * gridDim.y * gridDim.z;
        int lf = (flat & 7) * (nwg >> 3) + (flat >> 3);
        bx = lf % gridDim.x;
        int r = lf / gridDim.x;
        by = r % gridDim.y;
        bz = r / gridDim.y;
    }
    const int z1 = bz / nb2, z2 = bz % nb2;
    A += z1 * sA1 + z2 * sA2;
    B += z1 * sB1 + z2 * sB2;

    const int m0 = by * BM;
    const int n0 = bx * BN;
    const int tid = threadIdx.x;
    const int lane = tid & 63;
    const int wid = tid >> 6;
    const int wm = wid >> 1, wn = wid & 1;
    const int l15 = lane & 15;
    const int l4  = lane >> 4;

    __shared__ __align__(16) u16 As[NBUF][BM * 32];
    __shared__ __align__(16) u16 Bs[NBUF][BN * 32];

    auto stage = [&](int buf, int k0) {
        #pragma unroll
        for (int j = 0; j < nA / 4 + 1; ++j) {
            int jj = wid + j * 4;
            if (jj < nA) {
                int c = jj * 64 + lane;
                int row = c >> 2;
                int ksg = (c & 3) ^ ((row >> 1) & 3);   // pre-swizzled source chunk
                const u16* src = A + (long long)(m0 + row) * lda + k0 + ksg * 8;
                __builtin_amdgcn_global_load_lds((const GLOBAL_AS void*)src,
                                                 (LDS_AS void*)&As[buf][jj * 512], 16, 0, 0);
            }
        }
        #pragma unroll
        for (int j = 0; j < nB / 4 + 1; ++j) {
            int jj = wid + j * 4;
            if (jj < nB) {
                int c = jj * 64 + lane;
                int row = c >> 2;
                int ksg = (c & 3) ^ ((row >> 1) & 3);
                const u16* src = B + (long long)(n0 + row) * ldb + k0 + ksg * 8;
                __builtin_amdgcn_global_load_lds((const GLOBAL_AS void*)src,
                                                 (LDS_AS void*)&Bs[buf][jj * 512], 16, 0, 0);
            }
        }
    };

    f32x4 acc[MFR][NFR];
    #pragma unroll
    for (int i = 0; i < MFR; ++i)
        #pragma unroll
        for (int j = 0; j < NFR; ++j)
            acc[i][j] = (f32x4)0.0f;

    const int nk = K >> 5;

    if (DEEP) {
        constexpr int LPW = nA / 4 + nB / 4;    // loads per wave per stage
        stage(0, 0);
        if (nk > 1) stage(1, 32);
        for (int ki = 0; ki < nk; ++ki) {
            const int r = ki % 3;
            if (ki + 1 < nk)
                asm volatile("s_waitcnt vmcnt(%0)" :: "i"(LPW) : "memory");
            else
                asm volatile("s_waitcnt vmcnt(0)" ::: "memory");
            __builtin_amdgcn_s_barrier();
            __builtin_amdgcn_sched_barrier(0);

            short8 a[MFR], b[NFR];
            #pragma unroll
            for (int mf = 0; mf < MFR; ++mf) {
                int row = wm * 16 * MFR + mf * 16 + l15;
                int ksl = l4 ^ ((row >> 1) & 3);
                a[mf] = *(const short8*)&As[r][row * 32 + ksl * 8];
            }
            #pragma unroll
            for (int nf = 0; nf < NFR; ++nf) {
                int row = wn * 16 * NFR + nf * 16 + l15;
                int ksl = l4 ^ ((row >> 1) & 3);
                b[nf] = *(const short8*)&Bs[r][row * 32 + ksl * 8];
            }
            if (ki + 2 < nk) stage((ki + 2) % 3, (ki + 2) << 5);

            __builtin_amdgcn_s_setprio(1);
            #pragma unroll
            for (int mf = 0; mf < MFR; ++mf)
                #pragma unroll
                for (int nf = 0; nf < NFR; ++nf)
                    acc[mf][nf] = __builtin_amdgcn_mfma_f32_16x16x32_bf16(
                        a[mf], b[nf], acc[mf][nf], 0, 0, 0);
            __builtin_amdgcn_s_setprio(0);
        }
    } else {
        stage(0, 0);
        int cur = 0;
        for (int ki = 0; ki < nk; ++ki) {
            __syncthreads();
            if (ki + 1 < nk) stage(cur ^ 1, (ki + 1) << 5);

            short8 a[MFR], b[NFR];
            #pragma unroll
            for (int mf = 0; mf < MFR; ++mf) {
                int row = wm * 16 * MFR + mf * 16 + l15;
                int ksl = l4 ^ ((row >> 1) & 3);
                a[mf] = *(const short8*)&As[cur][row * 32 + ksl * 8];
            }
            #pragma unroll
            for (int nf = 0; nf < NFR; ++nf) {
                int row = wn * 16 * NFR + nf * 16 + l15;
                int ksl = l4 ^ ((row >> 1) & 3);
                b[nf] = *(const short8*)&Bs[cur][row * 32 + ksl * 8];
            }
            __builtin_amdgcn_s_setprio(1);
            #pragma unroll
            for (int mf = 0; mf < MFR; ++mf)
                #pragma unroll
                for (int nf = 0; nf < NFR; ++nf)
                    acc[mf][nf] = __builtin_amdgcn_mfma_f32_16x16x32_bf16(
                        a[mf], b[nf], acc[mf][nf], 0, 0, 0);
            __builtin_amdgcn_s_setprio(0);
            cur ^= 1;
        }
    }

    if (OUTMODE == 2) {
        u16* C = (u16*)Cv + z1 * sC1 + z2 * sC2;
        float rowp[MFR][4];
        #pragma unroll
        for (int mf = 0; mf < MFR; ++mf)
            #pragma unroll
            for (int r = 0; r < 4; ++r)
                rowp[mf][r] = 0.f;
        #pragma unroll
        for (int mf = 0; mf < MFR; ++mf) {
            #pragma unroll
            for (int nf = 0; nf < NFR; ++nf) {
                int r0 = m0 + wm * 16 * MFR + mf * 16 + l4 * 4;
                int c0 = n0 + wn * 16 * NFR + nf * 16 + l15;
                #pragma unroll
                for (int r = 0; r < 4; ++r) {
                    int row = r0 + r;
                    int vlen = STARTP + (row & 31) + 1;
                    float p = (c0 < vlen) ? __expf(acc[mf][nf][r] * ATT_SCALE) : 0.f;
                    u16 pb = f2b(p);
                    C[(long long)row * ldc + c0] = pb;
                    rowp[mf][r] += b2f(pb);
                }
            }
        }
        #pragma unroll
        for (int mf = 0; mf < MFR; ++mf)
            #pragma unroll
            for (int r = 0; r < 4; ++r) {
                float v = rowp[mf][r];
                v += __shfl_xor(v, 1);
                v += __shfl_xor(v, 2);
                v += __shfl_xor(v, 4);
                v += __shfl_xor(v, 8);
                if (l15 == 0) {
                    int row = m0 + wm * 16 * MFR + mf * 16 + l4 * 4 + r;
                    atomicAdd(&rs[z1 * 512 + row], v);
                }
            }
    } else if (OUTMODE == 1) {
        u16* C = (u16*)Cv + z1 * sC1 + z2 * sC2;
        #pragma unroll
        for (int mf = 0; mf < MFR; ++mf)
            #pragma unroll
            for (int nf = 0; nf < NFR; ++nf) {
                int r0 = m0 + wm * 16 * MFR + mf * 16 + l4 * 4;
                int c0 = n0 + wn * 16 * NFR + nf * 16 + l15;
                #pragma unroll
                for (int r = 0; r < 4; ++r)
                    C[(long long)(r0 + r) * ldc + c0] = f2b(acc[mf][nf][r]);
            }
    } else {
        float* C = (float*)Cv + z1 * sC1 + z2 * sC2;
        #pragma unroll
        for (int mf = 0; mf < MFR; ++mf)
            #pragma unroll
            for (int nf = 0; nf < NFR; ++nf) {
                int r0 = m0 + wm * 16 * MFR + mf * 16 + l4 * 4;
                int c0 = n0 + wn * 16 * NFR + nf * 16 + l15;
                #pragma unroll
                for (int r = 0; r < 4; ++r)
                    C[(long long)(r0 + r) * ldc + c0] = acc[mf][nf][r];
            }
    }
}

// ---------------------------------------------------------------------------
struct Segs {
    const float* src[6];
    u16* dst[6];
    int n4[6];
};
__global__ __launch_bounds__(256) void f2b_multi(Segs s)
{
    int seg = blockIdx.y;
    int i = blockIdx.x * 256 + threadIdx.x;
    if (i >= s.n4[seg]) return;
    float4 v = ((const float4*)s.src[seg])[i];
    u16x4 o = { f2b(v.x), f2b(v.y), f2b(v.z), f2b(v.w) };
    ((u16x4*)s.dst[seg])[i] = o;
}

// Zero the 4096-float rowsum buffer (ws is poisoned each launch).
__global__ __launch_bounds__(256) void rs_zero(float* __restrict__ rs)
{
    int i = blockIdx.x * 256 + threadIdx.x;
    float4 z = { 0.f, 0.f, 0.f, 0.f };
    ((float4*)rs)[i] = z;
}

// Sum 4 split-K partials (cols 0..767 of fused down output), RMS-norm -> bf16.
__global__ __launch_bounds__(256) void rms_reduce(const float* __restrict__ part,
                                                  const float* __restrict__ w,
                                                  u16* __restrict__ outb)
{
    const int row = blockIdx.x;          // 0..255
    const int tid = threadIdx.x;
    __shared__ float red[256];
    float val[3];
    float s = 0.f;
    #pragma unroll
    for (int j = 0; j < 3; ++j) {
        int i = tid + j * 256;
        long long off = (long long)row * NDOWN + i;
        float v = part[off] + part[DPART + off] + part[2 * DPART + off] + part[3 * DPART + off];
        val[j] = v;
        s += v * v;
    }
    red[tid] = s; __syncthreads();
    for (int off = 128; off > 0; off >>= 1) {
        if (tid < off) red[tid] += red[tid + off];
        __syncthreads();
    }
    float scale = rsqrtf(red[0] / (float)Q_RANK + RMS_EPS);
    u16* ob = outb + (long long)row * Q_RANK;
    #pragma unroll
    for (int j = 0; j < 3; ++j) {
        int i = tid + j * 256;
        ob[i] = f2b(val[j] * scale * w[i]);
    }
}

// Transpose w_kv_up[:, :128] per head: fp32 (h,128,512) -> bf16 wuT (h,512,128)
__global__ __launch_bounds__(256) void wuT_kernel(const float* __restrict__ w,
                                                  u16* __restrict__ outp)
{
    __shared__ u16 T[64][65];
    const int h = blockIdx.z;
    const int y0 = blockIdx.y * 64;
    const int x0 = blockIdx.x * 64;
    const int tid = threadIdx.x;
    #pragma unroll
    for (int i = 0; i < 16; ++i) {
        int lin = i * 256 + tid;
        int r = lin >> 6, c = lin & 63;
        T[c][r] = f2b(w[((long long)h * 256 + y0 + r) * 512 + x0 + c]);
    }
    __syncthreads();
    #pragma unroll
    for (int i = 0; i < 16; ++i) {
        int lin = i * 256 + tid;
        int r = lin >> 6, c = lin & 63;
        outp[((long long)h * 512 + x0 + r) * 128 + y0 + c] = T[r][c];
    }
}

// Sum 4 kv split-K partials; write new bcat rows (latent + roped k_rope).
__global__ __launch_bounds__(256) void bcat_new_reduce(const float* __restrict__ part,
                                                       const float* __restrict__ fc,
                                                       const float* __restrict__ fs,
                                                       u16* __restrict__ bcat)
{
    const int bl = blockIdx.x;        // 0..255
    const int b = bl >> 5, l = bl & 31;
    const int t = threadIdx.x;
    if (t >= 144) return;
    long long off = (long long)bl * NDOWN + 768 + 4 * t;
    float4 v0 = *(const float4*)(part + off);
    float4 v1 = *(const float4*)(part + DPART + off);
    float4 v2 = *(const float4*)(part + 2 * DPART + off);
    float4 v3 = *(const float4*)(part + 3 * DPART + off);
    float4 v = { v0.x + v1.x + v2.x + v3.x, v0.y + v1.y + v2.y + v3.y,
                 v0.z + v1.z + v2.z + v3.z, v0.w + v1.w + v2.w + v3.w };
    u16* dst = bcat + ((long long)b * MAX_T + STARTP + l) * 576;
    if (t < 128) {
        u16x4 o = { f2b(v.x), f2b(v.y), f2b(v.z), f2b(v.w) };
        ((u16x4*)dst)[t] = o;
    } else {
        int g = t - 128;
        float c0 = fc[l * 32 + 2 * g],     s0 = fs[l * 32 + 2 * g];
        float c1 = fc[l * 32 + 2 * g + 1], s1 = fs[l * 32 + 2 * g + 1];
        u16x4 o = { f2b(v.x * c0 - v.y * s0), f2b(v.x * s0 + v.y * c0),
                    f2b(v.z * c1 - v.w * s1), f2b(v.z * s1 + v.w * c1) };
        *(u16x4*)(dst + 512 + 4 * g) = o;
    }
}

// ---------------------------------------------------------------------------
// Cache prep, 16 B stores. XOR-swizzled LDS.
// ---------------------------------------------------------------------------
__global__ __launch_bounds__(256) void prep_cache(const float* __restrict__ kvc,
                                                  const float* __restrict__ krc,
                                                  u16* __restrict__ bcat,
                                                  u16* __restrict__ kvcT)
{
    const int b = blockIdx.z;
    const int t0 = blockIdx.y * 64;
    const int tid = threadIdx.x;

    if (blockIdx.x == 8) {
        #pragma unroll
        for (int i = 0; i < 2; ++i) {
            int lin = i * 256 + tid;
            int r = lin >> 3, c8 = lin & 7;
            int t = t0 + r;
            if (t >= STARTP) continue;
            const float* src = krc + ((long long)b * MAX_T + t) * D_R + 8 * c8;
            float4 v0 = *(const float4*)src;
            float4 v1 = *(const float4*)(src + 4);
            u16x8 o = { f2b(v0.x), f2b(v0.y), f2b(v0.z), f2b(v0.w),
                        f2b(v1.x), f2b(v1.y), f2b(v1.z), f2b(v1.w) };
            *(u16x8*)(bcat + ((long long)b * MAX_T + t) * 576 + 512 + 8 * c8) = o;
        }
        return;
    }

    __shared__ u16 T[64 * 64];
    const int k0 = blockIdx.x * 64;

    #pragma unroll
    for (int i = 0; i < 2; ++i) {
        int lin = i * 256 + tid;
        int r = lin >> 3, c8 = lin & 7;
        int t = t0 + r;
        u16x4 oa, ob;
        if (t < STARTP) {
            const float* src = kvc + ((long long)b * MAX_T + t) * KV_RANK + k0 + 8 * c8;
            float4 v0 = *(const float4*)src;
            float4 v1 = *(const float4*)(src + 4);
            oa[0] = f2b(v0.x); oa[1] = f2b(v0.y); oa[2] = f2b(v0.z); oa[3] = f2b(v0.w);
            ob[0] = f2b(v1.x); ob[1] = f2b(v1.y); ob[2] = f2b(v1.z); ob[3] = f2b(v1.w);
            u16x8 o = { oa[0], oa[1], oa[2], oa[3], ob[0], ob[1], ob[2], ob[3] };
            *(u16x8*)(bcat + ((long long)b * MAX_T + t) * 576 + k0 + 8 * c8) = o;
        } else {
            const u16* s = bcat + ((long long)b * MAX_T + t) * 576 + k0 + 8 * c8;
            oa = *(const u16x4*)s;
            ob = *(const u16x4*)(s + 4);
        }
        int tg = r >> 2, te = r & 3;
        int c4a = 2 * c8, c4b = 2 * c8 + 1;
        int cola = ((tg ^ c4a) << 2) + te;
        int colb = ((tg ^ c4b) << 2) + te;
        #pragma unroll
        for (int j = 0; j < 4; ++j) {
            T[(4 * c4a + j) * 64 + cola] = oa[j];
            T[(4 * c4b + j) * 64 + colb] = ob[j];
        }
    }
    __syncthreads();

    u16* outp = kvcT + ((long long)b * KV_RANK + k0) * MAX_T + t0;
    #pragma unroll
    for (int i = 0; i < 2; ++i) {
        int lin = i * 256 + tid;
        int k = lin >> 3, c8 = lin & 7;
        int s = k >> 2;
        u16x4 va = *(const u16x4*)&T[k * 64 + (((2 * c8) ^ s) << 2)];
        u16x4 vb = *(const u16x4*)&T[k * 64 + (((2 * c8 + 1) ^ s) << 2)];
        u16x8 o = { va[0], va[1], va[2], va[3], vb[0], vb[1], vb[2], vb[3] };
        *(u16x8*)(outp + (long long)k * MAX_T + 8 * c8) = o;
    }
}

// roped q_rope (bf16 q in) -> qprimeb[b,h,l,512:576]
__global__ __launch_bounds__(256) void rope_q(const u16* __restrict__ qb,
                                              const float* __restrict__ fc,
                                              const float* __restrict__ fs,
                                              u16* __restrict__ qprimeb)
{
    int idx = blockIdx.x * 256 + threadIdx.x;
    int i = idx & 31;
    int h = (idx >> 5) & (NH - 1);
    int l = (idx >> 9) & (NL - 1);
    int b = idx >> 14;
    const u16* src = qb + (long long)(b * NL + l) * 3072 + h * QK_DIM + D_NR + 2 * i;
    float xr = b2f(src[0]), xi = b2f(src[1]);
    float c = fc[l * 32 + i], s = fs[l * 32 + i];
    u16* dst = qprimeb + ((long long)(b * NH + h) * NL + l) * 576 + 512 + 2 * i;
    dst[0] = f2b(xr * c - xi * s);
    dst[1] = f2b(xr * s + xi * c);
}

// Sum 4 PV split-K partials, normalize by rowsum -> bf16 o_hb.
__global__ __launch_bounds__(256) void reduce_pv(const float* __restrict__ part,
                                                 const float* __restrict__ rs,
                                                 u16* __restrict__ o_hb)
{
    int idx = blockIdx.x * 256 + threadIdx.x;     // < 524288
    int b = idx >> 16;
    int i4 = idx & 65535;
    int m = i4 >> 7;                               // row (h*32+l) within b
    const float* p = part + (long long)b * 1048576 + 4 * i4;
    float4 v0 = *(const float4*)p;
    float4 v1 = *(const float4*)(p + 262144);
    float4 v2 = *(const float4*)(p + 524288);
    float4 v3 = *(const float4*)(p + 786432);
    float inv = 1.0f / rs[b * 512 + m];
    u16x4 o = { f2b((v0.x + v1.x + v2.x + v3.x) * inv),
                f2b((v0.y + v1.y + v2.y + v3.y) * inv),
                f2b((v0.z + v1.z + v2.z + v3.z) * inv),
                f2b((v0.w + v1.w + v2.w + v3.w) * inv) };
    ((u16x4*)(o_hb + (long long)b * 262144))[i4] = o;
}

// Sum 4 out-proj split-K partials -> fp32 out. 131072 float4 groups.
__global__ __launch_bounds__(256) void reduce_out(const float* __restrict__ part,
                                                  float* __restrict__ out)
{
    int idx = blockIdx.x * 256 + threadIdx.x;     // < 131072
    const float* p = part + 4 * (long long)idx;
    float4 v0 = *(const float4*)p;
    float4 v1 = *(const float4*)(p + 524288);
    float4 v2 = *(const float4*)(p + 1048576);
    float4 v3 = *(const float4*)(p + 1572864);
    float4 o = { v0.x + v1.x + v2.x + v3.x, v0.y + v1.y + v2.y + v3.y,
                 v0.z + v1.z + v2.z + v3.z, v0.w + v1.w + v2.w + v3.w };
    ((float4*)out)[idx] = o;
}

extern "C" void kernel_launch(void* const* d_in, const int* in_sizes, int n_in,
                              void* d_out, int out_size, void* d_ws, size_t ws_size,
                              hipStream_t stream)
{
    const float* x        = (const float*)d_in[0];
    const float* fc       = (const float*)d_in[2];
    const float* fs       = (const float*)d_in[3];
    const float* kvc      = (const float*)d_in[5];
    const float* krc      = (const float*)d_in[6];
    const float* w_kv_down= (const float*)d_in[7];
    const float* w_q_down = (const float*)d_in[8];
    const float* rms_q_w  = (const float*)d_in[9];
    const float* w_q_up   = (const float*)d_in[10];
    const float* w_kv_up  = (const float*)d_in[11];
    const float* w_out    = (const float*)d_in[12];
    float* out            = (float*)d_out;

    // ---- workspace layout ----
    float* down_part = (float*)d_ws;             // 4 x 256x1344 = 1376256 f
    float* rs      = down_part + 1376256;        // 4096 f rowsum (b,512)
    u16* pb        = (u16*)(rs + 4096);          // P~ bf16 (b,512,4096)
    u16* base      = pb + 16777216;
    u16* xb      = base;                 base += 524288;    // 256x2048
    u16* qdb     = base;                 base += 196608;    // 256x768
    u16* qb      = base;                 base += 786432;    // 256x3072
    u16* qprimeb = base;                 base += 2359296;   // (b,h,l,576)
    u16* wqkv_b  = base;                 base += 2752512;   // [w_q_down;w_kv_down]
    u16* wqu_b   = base;                 base += 2359296;   // 3072x768
    u16* wkvu_b  = base;                 base += 2097152;   // 4096x512
    u16* wout_b  = base;                 base += 4194304;   // 2048x2048
    u16* wuT     = base;                 base += 1048576;   // (h,512,128)
    u16* bcat    = base;                 base += 18874368;  // (b,4096,576)
    u16* kvcT    = base;                 base += 16777216;  // (b,512,4096)
    u16* o_hb    = base;                 base += 2097152;   // (b,512,512)
    u16* o_upb   = base;                 base += 524288;    // 256x2048
    // aliases over dead regions:
    float* pv_part  = (float*)bcat;   // 32 MB, after scores GEMM (bcat dead)
    float* out_part = (float*)kvcT;   // 8 MB, after PV (kvcT dead)

    // 1) fp32->bf16 conversions
    Segs segs;
    segs.src[0] = x;         segs.dst[0] = xb;                  segs.n4[0] = 131072;
    segs.src[1] = w_q_down;  segs.dst[1] = wqkv_b;              segs.n4[1] = 393216;
    segs.src[2] = w_q_up;    segs.dst[2] = wqu_b;               segs.n4[2] = 589824;
    segs.src[3] = w_kv_down; segs.dst[3] = wqkv_b + 768 * 2048; segs.n4[3] = 294912;
    segs.src[4] = w_kv_up;   segs.dst[4] = wkvu_b;              segs.n4[4] = 524288;
    segs.src[5] = w_out;     segs.dst[5] = wout_b;              segs.n4[5] = 1048576;
    f2b_multi<<<dim3(4096, 6), 256, 0, stream>>>(segs);

    rs_zero<<<4, 256, 0, stream>>>(rs);
    wuT_kernel<<<dim3(8, 2, 16), 256, 0, stream>>>(w_kv_up, wuT);

    // 2) fused down-proj split-K=4
    gemm_mfma<32, 64, 0, true, false><<<dim3(21, 8, 4), 256, 0, stream>>>(
        xb, wqkv_b, down_part, nullptr, 512, 2048, 2048, NDOWN,
        0LL, 512LL, 0LL, 512LL, 0LL, DPART, 4);
    // 3) reduce + RMS -> bf16
    rms_reduce<<<256, 256, 0, stream>>>(down_part, rms_q_w, qdb);
    // 4) q = qn @ w_q_up^T  (256,3072,768) bf16
    gemm_mfma<32, 64, 1, true, false><<<dim3(48, 8, 1), 256, 0, stream>>>(
        qdb, wqu_b, qb, nullptr, 768, 768, 768, 3072, 0, 0, 0, 0, 0, 0, 1);
    // 5) reduce kv part + new bcat rows
    bcat_new_reduce<<<256, 256, 0, stream>>>(down_part, fc, fs, bcat);
    // 6) cache prep
    prep_cache<<<dim3(9, 64, 8), 256, 0, stream>>>(kvc, krc, bcat, kvcT);

    // 7) q_abs per (b,h); rope
    gemm_mfma<32, 128, 1, true, false><<<dim3(4, 1, 128), 256, 0, stream>>>(
        qb, wuT, qprimeb, nullptr, 128, 3072, 128, 576,
        98304LL, 192LL, 0LL, 65536LL, 294912LL, 18432LL, 16);
    rope_q<<<512, 256, 0, stream>>>(qb, fc, fs, qprimeb);

    // 8) scores+exp+mask+rowsum (DEEP counted-vmcnt pipeline)
    gemm_mfma<128, 128, 2, true, true><<<dim3(32, 4, 8), 256, 0, stream>>>(
        qprimeb, bcat, pb, rs, 576, 576, 576, 4096,
        294912LL, 0LL, 2359296LL, 0LL, 2097152LL, 0LL, 1);
    // 9) PV split-K=4 (DEEP)
    gemm_mfma<128, 128, 0, true, true><<<dim3(4, 4, 32), 256, 0, stream>>>(
        pb, kvcT, pv_part, nullptr, 1024, 4096, 4096, 512,
        2097152LL, 1024LL, 2097152LL, 1024LL, 1048576LL, 262144LL, 4);
    // 10) reduce + normalize -> bf16 o_hb
    reduce_pv<<<2048, 256, 0, stream>>>(pv_part, rs, o_hb);

    // 11) o_up per (b,h)
    gemm_mfma<32, 64, 1, true, false><<<dim3(2, 1, 128), 256, 0, stream>>>(
        o_hb, wkvu_b + 128 * 512, o_upb, nullptr, 512, 512, 512, 2048,
        262144LL, 16384LL, 0LL, 131072LL, 65536LL, 128LL, 16);
    // 12) out-proj split-K=4, reduce -> out
    gemm_mfma<32, 64, 0, true, false><<<dim3(32, 8, 4), 256, 0, stream>>>(
        o_upb, wout_b, out_part, nullptr, 512, 2048, 2048, 2048,
        0LL, 512LL, 0LL, 512LL, 0LL, 524288LL, 4);
    reduce_out<<<512, 256, 0, stream>>>(out_part, out);
}